// Round 6
// baseline (215.361 us; speedup 1.0000x reference)
//
#include <hip/hip_runtime.h>
#include <stdint.h>

#define BB 16384
#define PR2 16896     // 16384 + 8*64 worst-case bucket padding (64-granular)
#define MAXT2 264     // PR2/64 = 8*33

typedef short bf16x8 __attribute__((ext_vector_type(8)));
typedef float f32x4 __attribute__((ext_vector_type(4)));
typedef unsigned short us4v __attribute__((ext_vector_type(4)));

typedef __attribute__((address_space(1))) unsigned short gus_t;
typedef __attribute__((address_space(3))) unsigned short lus_t;

__device__ __forceinline__ unsigned short f2bf(float f) {
    unsigned int u = __float_as_uint(f);
    u += 0x7fffu + ((u >> 16) & 1u);   // RNE
    return (unsigned short)(u >> 16);
}
__device__ __forceinline__ float bf2f(unsigned short h) {
    return __uint_as_float(((unsigned int)h) << 16);
}

__device__ __forceinline__ void gld16(const unsigned short* g, unsigned short* l) {
    __builtin_amdgcn_global_load_lds(
        reinterpret_cast<const gus_t*>(reinterpret_cast<uintptr_t>(g)),
        reinterpret_cast<lus_t*>(reinterpret_cast<uintptr_t>(l)),
        16, 0, 0);
}

// ---------------- weight conversion ----------------
__global__ void cvt_bf16(const float* __restrict__ src, unsigned short* __restrict__ dst, int n4) {
    int stride = gridDim.x * blockDim.x;
    for (int i = blockIdx.x * blockDim.x + threadIdx.x; i < n4; i += stride) {
        f32x4 v = reinterpret_cast<const f32x4*>(src)[i];
        us4v o;
        o[0] = f2bf(v[0]); o[1] = f2bf(v[1]); o[2] = f2bf(v[2]); o[3] = f2bf(v[3]);
        reinterpret_cast<us4v*>(dst)[i] = o;
    }
}

// ---------------- bucketing (64-granular, block-aggregated atomics) ----------------
__global__ void bucket_init(int* perm, int* counts, int* cursors, int* tile_exp) {
    int i = blockIdx.x * blockDim.x + threadIdx.x;
    if (i < PR2) perm[i] = -1;
    if (i < 8) { counts[i] = 0; cursors[i] = 0; }
    if (i < MAXT2) tile_exp[i] = 0;
}

__global__ __launch_bounds__(1024) void bucket_count(const int* __restrict__ y, int* counts) {
    __shared__ int lc[8];
    const int t = threadIdx.x;
    if (t < 8) lc[t] = 0;
    __syncthreads();
    atomicAdd(&lc[y[blockIdx.x * 1024 + t]], 1);
    __syncthreads();
    if (t < 8) atomicAdd(&counts[t], lc[t]);
}

__global__ void bucket_scan(const int* __restrict__ counts, int* starts, int* tile_exp) {
    if (threadIdx.x == 0 && blockIdx.x == 0) {
        int s = 0;
        for (int e = 0; e < 8; ++e) {
            starts[e] = s;
            int nt = (counts[e] + 63) >> 6;
            for (int t = 0; t < nt; ++t) tile_exp[(s >> 6) + t] = e;
            s += nt << 6;
        }
        starts[8] = s;   // total padded rows (multiple of 64)
    }
}

__global__ __launch_bounds__(1024) void bucket_scatter(const int* __restrict__ y,
                                                       const int* __restrict__ starts,
                                                       int* cursors, int* perm) {
    __shared__ int lc[8];
    __shared__ int lbase[8];
    const int t = threadIdx.x;
    if (t < 8) lc[t] = 0;
    __syncthreads();
    const int i = blockIdx.x * 1024 + t;
    const int e = y[i];
    const int r = atomicAdd(&lc[e], 1);
    __syncthreads();
    if (t < 8) lbase[t] = atomicAdd(&cursors[t], lc[t]);
    __syncthreads();
    perm[starts[e] + lbase[e] + r] = i;
}

// ---------------- fused 4-layer MLP, 64 rows x 512 cols resident in LDS ----------------
// Same layouts as R5 (numerics verified). New: T3/T4 pipeline — raw s_barrier +
// counted vmcnt, 2-step-deep W prefetch; loads never drained to 0 in the loop.
// Per stage: 4 gld16/thread (=4 vmcnt ops/wave). Steady state: 8 outstanding,
// wait vmcnt(4) retires current buffer. Biases prefetched + vmcnt(0)-fenced in
// prologue so staging loads are the only vmcnt traffic in the loop.
#define STAGEW64(s_, buf_) do {                                          \
    const unsigned short* wp_ = Wl + ((s_) >> 4) * 262144                \
                              + (((s_) & 15) << 5) + wbase;              \
    unsigned short* ld_ = lsW + ((buf_) << 14) + (t << 3);               \
    gld16(wp_,          ld_);                                            \
    gld16(wp_ +  65536, ld_ +  4096);                                    \
    gld16(wp_ + 131072, ld_ +  8192);                                    \
    gld16(wp_ + 196608, ld_ + 12288);                                    \
} while (0)

template <int PHASE>
__global__ __launch_bounds__(512) void fused4(
    const float* __restrict__ sf32,
    const unsigned short* __restrict__ srelg,
    const unsigned short* __restrict__ Wb,
    const float* __restrict__ biasb,
    unsigned short* __restrict__ srel_out,
    unsigned short* __restrict__ h_out,
    const unsigned short* __restrict__ h_in,
    float* __restrict__ outf,
    const int* __restrict__ perm,
    const int* __restrict__ tile_exp,
    const int* __restrict__ starts8)
{
    __shared__ __align__(16) unsigned short lsA[32768];   // 64 KB activations
    __shared__ __align__(16) unsigned short lsW[32768];   // 64 KB: 2x32KB W dbuf
    __shared__ int lperm[64];

    const int bid = blockIdx.x;
    int tile;
    if (PHASE == 0) {
        tile = ((bid & 7) << 5) + (bid >> 3);             // XCD swizzle, 256 = 8*32
    } else {
        tile = (bid & 7) * 33 + (bid >> 3);               // XCD swizzle, 264 = 8*33
        if ((tile << 6) >= starts8[0]) return;
    }

    const unsigned short* Wl;
    const float* bl;
    if (PHASE == 0) { Wl = Wb; bl = biasb; }
    else {
        const int e = tile_exp[tile];
        Wl = Wb + ((size_t)e << 20);
        bl = biasb + (e << 11);
    }

    const int t = threadIdx.x;
    const int w = t >> 6;
    const int lane = t & 63;
    const int lr = lane & 15;
    const int kg = lane >> 4;

    const int wbase = ((t >> 2) << 9) + (((t & 3) ^ ((t >> 3) & 3)) << 3);
    const int asrc_c = (t & 56) | ((t ^ (t >> 6)) & 7);
    const int axor = lr & 7;
    int arow_e[4], bvo[4];
#pragma unroll
    for (int m = 0; m < 4; ++m) arow_e[m] = ((m << 4) + lr) << 9;
#pragma unroll
    for (int j = 0; j < 4; ++j)
        bvo[j] = (((w << 6) + (j << 4) + lr) << 5) + ((kg ^ ((lr >> 1) & 3)) << 3);

    // ---- prologue: biases for ALL layers, fenced before any gld16 ----
    float bball[16];
#pragma unroll
    for (int l = 0; l < 4; ++l)
#pragma unroll
        for (int j = 0; j < 4; ++j)
            bball[(l << 2) + j] = bl[(l << 9) + (w << 6) + (j << 4) + lr];
    asm volatile("s_waitcnt vmcnt(0)" ::: "memory");

    // ---- initial A stage ----
    if (PHASE == 0) {
#pragma unroll
        for (int c8 = 0; c8 < 8; ++c8) {
            const int grow = (tile << 6) + (c8 << 3) + (t >> 6);
            const float* sp = sf32 + (((size_t)grow) << 9) + (asrc_c << 3);
            f32x4 v0 = *reinterpret_cast<const f32x4*>(sp);
            f32x4 v1 = *reinterpret_cast<const f32x4*>(sp + 4);
            bf16x8 o;
#pragma unroll
            for (int q = 0; q < 4; ++q) { o[q] = (short)f2bf(v0[q]); o[q + 4] = (short)f2bf(v1[q]); }
            *reinterpret_cast<bf16x8*>(&lsA[(c8 << 12) + (t << 3)]) = o;
        }
    } else {
        if (t < 64) lperm[t] = perm[(tile << 6) + t];
        __syncthreads();
#pragma unroll
        for (int c8 = 0; c8 < 8; ++c8) {
            int pr = lperm[(c8 << 3) + (t >> 6)];
            if (pr < 0) pr = 0;
            gld16(srelg + (((size_t)pr) << 9) + (asrc_c << 3), lsA + (c8 << 12) + (t << 3));
        }
    }
    STAGEW64(0, 0);
    STAGEW64(1, 1);
    asm volatile("s_waitcnt lgkmcnt(0)" ::: "memory");   // phase-0 lsA writes done

    f32x4 acc[4][4];
#pragma unroll
    for (int m = 0; m < 4; ++m)
#pragma unroll
        for (int j = 0; j < 4; ++j)
            acc[m][j] = f32x4{0.f, 0.f, 0.f, 0.f};

    // ---- main loop: 64 K-steps (4 layers x 16), 2-deep pipelined ----
    for (int s = 0; s < 64; ++s) {
        if (s < 63) asm volatile("s_waitcnt vmcnt(4)" ::: "memory");
        else        asm volatile("s_waitcnt vmcnt(0)" ::: "memory");
        __builtin_amdgcn_s_barrier();                    // buf(s&1) fully staged
        __builtin_amdgcn_sched_barrier(0);

        const int st = s & 15;
        const int sb = (st >> 1) << 6;
        const int klo = ((((st & 1) << 2) | kg) ^ axor) << 3;
        const int wbuf = (s & 1) << 14;
        bf16x8 af[4], bv[4];
#pragma unroll
        for (int m = 0; m < 4; ++m)
            af[m] = *reinterpret_cast<const bf16x8*>(&lsA[arow_e[m] + sb + klo]);
#pragma unroll
        for (int j = 0; j < 4; ++j)
            bv[j] = *reinterpret_cast<const bf16x8*>(&lsW[wbuf + bvo[j]]);
        asm volatile("s_waitcnt lgkmcnt(0)" ::: "memory");
        __builtin_amdgcn_s_barrier();                    // all waves read buf -> free
        __builtin_amdgcn_sched_barrier(0);

        if (s + 2 < 64) STAGEW64(s + 2, s & 1);          // refill freed buffer
        __builtin_amdgcn_sched_barrier(0);

        __builtin_amdgcn_s_setprio(1);
#pragma unroll
        for (int m = 0; m < 4; ++m)
#pragma unroll
            for (int j = 0; j < 4; ++j)
                acc[m][j] = __builtin_amdgcn_mfma_f32_16x16x32_bf16(af[m], bv[j], acc[m][j], 0, 0, 0);
        __builtin_amdgcn_s_setprio(0);

        if (st == 15 && s < 63) {
            // layer boundary (l = s>>4 in {0,1,2}): relu + bf16 back into A-LDS
            const int lbb = (s >> 4) << 2;
#pragma unroll
            for (int m = 0; m < 4; ++m)
#pragma unroll
                for (int j = 0; j < 4; ++j) {
#pragma unroll
                    for (int reg = 0; reg < 4; ++reg) {
                        const int row = (m << 4) + (kg << 2) + reg;
                        const float v = fmaxf(acc[m][j][reg] + bball[lbb + j], 0.f);
                        const int swc = (w << 3) + (((j << 1) + (lr >> 3)) ^ (row & 7));
                        lsA[(row << 9) + (swc << 3) + (lr & 7)] = f2bf(v);
                    }
                    acc[m][j] = f32x4{0.f, 0.f, 0.f, 0.f};
                }
            asm volatile("s_waitcnt lgkmcnt(0)" ::: "memory");
            __builtin_amdgcn_s_barrier();
            __builtin_amdgcn_sched_barrier(0);
        }
    }

    // ---- final epilogue (bball[12..15] = layer-3 bias) ----
    if (PHASE == 0) {
#pragma unroll
        for (int m = 0; m < 4; ++m)
#pragma unroll
            for (int j = 0; j < 4; ++j)
#pragma unroll
                for (int reg = 0; reg < 4; ++reg) {
                    const int row = (m << 4) + (kg << 2) + reg;
                    const int col = (w << 6) + (j << 4) + lr;
                    const float h = fmaxf(acc[m][j][reg] + bball[12 + j], 0.f);
                    const float sv = sf32[(((size_t)((tile << 6) + row)) << 9) + col];
                    const int swc = (w << 3) + (((j << 1) + (lr >> 3)) ^ (row & 7));
                    const int idx = (row << 9) + (swc << 3) + (lr & 7);
                    lsA[idx] = f2bf(sv - h);
                    lsW[idx] = f2bf(h);
                }
        __syncthreads();
#pragma unroll
        for (int c8 = 0; c8 < 8; ++c8) {
            const int row = (c8 << 3) + (t >> 6);
            const size_t go = (((size_t)((tile << 6) + row)) << 9) + (asrc_c << 3);
            bf16x8 va = *reinterpret_cast<const bf16x8*>(&lsA[(c8 << 12) + (t << 3)]);
            bf16x8 vh = *reinterpret_cast<const bf16x8*>(&lsW[(c8 << 12) + (t << 3)]);
            *reinterpret_cast<bf16x8*>(&srel_out[go]) = va;
            *reinterpret_cast<bf16x8*>(&h_out[go]) = vh;
        }
    } else {
#pragma unroll
        for (int m = 0; m < 4; ++m)
#pragma unroll
            for (int j = 0; j < 4; ++j)
#pragma unroll
                for (int reg = 0; reg < 4; ++reg) {
                    const int row = (m << 4) + (kg << 2) + reg;
                    const int pr = lperm[row];
                    if (pr >= 0) {
                        const int col = (w << 6) + (j << 4) + lr;
                        const size_t gi = (((size_t)pr) << 9) + col;
                        outf[gi] = acc[m][j][reg] + bball[12 + j] + bf2f(h_in[gi]);
                    }
                }
    }
}

// ---------------- launch ----------------
extern "C" void kernel_launch(void* const* d_in, const int* in_sizes, int n_in,
                              void* d_out, int out_size, void* d_ws, size_t ws_size,
                              hipStream_t stream)
{
    const float* s     = (const float*)d_in[0];
    const int*   y     = (const int*)d_in[1];
    const float* dec_W = (const float*)d_in[2];
    const float* dec_b = (const float*)d_in[3];
    const float* exp_W = (const float*)d_in[4];
    const float* exp_b = (const float*)d_in[5];
    float* out = (float*)d_out;

    unsigned short* decWb = (unsigned short*)d_ws;              // 4*512*512 bf16 (2 MB)
    unsigned short* expWb = decWb + 4 * 512 * 512;              // 32*512*512 bf16 (16 MB)
    unsigned short* srel  = expWb + 8 * 4 * 512 * 512;          // BB*512 bf16 (16 MB)
    unsigned short* hbuf  = srel + (size_t)BB * 512;            // BB*512 bf16 (16 MB)
    int* perm     = (int*)(hbuf + (size_t)BB * 512);            // PR2
    int* counts   = perm + PR2;                                 // 8
    int* cursors  = counts + 8;                                 // 8
    int* starts   = cursors + 8;                                // 9
    int* tile_exp = starts + 9;                                 // MAXT2

    cvt_bf16<<<256, 256, 0, stream>>>(dec_W, decWb, (4 * 512 * 512) / 4);
    cvt_bf16<<<2048, 256, 0, stream>>>(exp_W, expWb, (8 * 4 * 512 * 512) / 4);

    bucket_init<<<(PR2 + 255) / 256, 256, 0, stream>>>(perm, counts, cursors, tile_exp);
    bucket_count<<<BB / 1024, 1024, 0, stream>>>(y, counts);
    bucket_scan<<<1, 64, 0, stream>>>(counts, starts, tile_exp);
    bucket_scatter<<<BB / 1024, 1024, 0, stream>>>(y, starts, cursors, perm);

    fused4<0><<<256, 512, 0, stream>>>(s, nullptr, decWb, dec_b, srel, hbuf,
                                       nullptr, nullptr, nullptr, nullptr, nullptr);
    fused4<1><<<MAXT2, 512, 0, stream>>>(nullptr, srel, expWb, exp_b, nullptr, nullptr,
                                         hbuf, out, perm, tile_exp, starts + 8);
}

// Round 7
// 191.976 us; speedup vs baseline: 1.1218x; 1.1218x over previous
//
#include <hip/hip_runtime.h>
#include <stdint.h>

#define BB 16384
#define PR2 16896     // 16384 + 8*64 worst-case bucket padding (64-granular)
#define MAXT2 264     // PR2/64 = 8*33

typedef short bf16x8 __attribute__((ext_vector_type(8)));
typedef float f32x4 __attribute__((ext_vector_type(4)));
typedef unsigned short us4v __attribute__((ext_vector_type(4)));

typedef __attribute__((address_space(1))) unsigned short gus_t;
typedef __attribute__((address_space(3))) unsigned short lus_t;

__device__ __forceinline__ unsigned short f2bf(float f) {
    unsigned int u = __float_as_uint(f);
    u += 0x7fffu + ((u >> 16) & 1u);   // RNE
    return (unsigned short)(u >> 16);
}
__device__ __forceinline__ float bf2f(unsigned short h) {
    return __uint_as_float(((unsigned int)h) << 16);
}

__device__ __forceinline__ void gld16(const unsigned short* g, unsigned short* l) {
    __builtin_amdgcn_global_load_lds(
        reinterpret_cast<const gus_t*>(reinterpret_cast<uintptr_t>(g)),
        reinterpret_cast<lus_t*>(reinterpret_cast<uintptr_t>(l)),
        16, 0, 0);
}

// ---------------- weight conversion ----------------
__global__ void cvt_bf16(const float* __restrict__ src, unsigned short* __restrict__ dst, int n4) {
    int stride = gridDim.x * blockDim.x;
    for (int i = blockIdx.x * blockDim.x + threadIdx.x; i < n4; i += stride) {
        f32x4 v = reinterpret_cast<const f32x4*>(src)[i];
        us4v o;
        o[0] = f2bf(v[0]); o[1] = f2bf(v[1]); o[2] = f2bf(v[2]); o[3] = f2bf(v[3]);
        reinterpret_cast<us4v*>(dst)[i] = o;
    }
}

// ---------------- bucketing (64-granular, block-aggregated atomics) ----------------
__global__ void bucket_init(int* perm, int* counts, int* cursors, int* tile_exp) {
    int i = blockIdx.x * blockDim.x + threadIdx.x;
    if (i < PR2) perm[i] = -1;
    if (i < 8) { counts[i] = 0; cursors[i] = 0; }
    if (i < MAXT2) tile_exp[i] = 0;
}

__global__ __launch_bounds__(1024) void bucket_count(const int* __restrict__ y, int* counts) {
    __shared__ int lc[8];
    const int t = threadIdx.x;
    if (t < 8) lc[t] = 0;
    __syncthreads();
    atomicAdd(&lc[y[blockIdx.x * 1024 + t]], 1);
    __syncthreads();
    if (t < 8) atomicAdd(&counts[t], lc[t]);
}

__global__ void bucket_scan(const int* __restrict__ counts, int* starts, int* tile_exp) {
    if (threadIdx.x == 0 && blockIdx.x == 0) {
        int s = 0;
        for (int e = 0; e < 8; ++e) {
            starts[e] = s;
            int nt = (counts[e] + 63) >> 6;
            for (int t = 0; t < nt; ++t) tile_exp[(s >> 6) + t] = e;
            s += nt << 6;
        }
        starts[8] = s;   // total padded rows (multiple of 64)
    }
}

__global__ __launch_bounds__(1024) void bucket_scatter(const int* __restrict__ y,
                                                       const int* __restrict__ starts,
                                                       int* cursors, int* perm) {
    __shared__ int lc[8];
    __shared__ int lbase[8];
    const int t = threadIdx.x;
    if (t < 8) lc[t] = 0;
    __syncthreads();
    const int i = blockIdx.x * 1024 + t;
    const int e = y[i];
    const int r = atomicAdd(&lc[e], 1);
    __syncthreads();
    if (t < 8) lbase[t] = atomicAdd(&cursors[t], lc[t]);
    __syncthreads();
    perm[starts[e] + lbase[e] + r] = i;
}

// ---------------- fused 4-layer MLP, 64 rows x 512 cols resident in LDS ----------------
// LDS (exactly 160 KiB): A = ls[0..32768) us (64 KB), W = 3 x 32 KB at ls+32768+b*16384.
// 3 W buffers -> ONE barrier per K-step: at the top-of-step barrier every wave has
// already consumed (lgkm-drained via its MFMAs) the buffer staged 2 steps ago, so
// restaging it is race-free without a second barrier. ds_reads and MFMAs share one
// region with no fences -> compiler emits counted lgkmcnt interleave (m97 behavior).
// vmcnt(4) at step top retires exactly the buffer needed now; never 0 in-loop.
#define STAGEW(s_, b_) do {                                              \
    const unsigned short* wp_ = Wl + ((s_) >> 4) * 262144                \
                              + (((s_) & 15) << 5) + wbase;              \
    unsigned short* ld_ = ls + 32768 + ((b_) << 14) + (t << 3);          \
    gld16(wp_,          ld_);                                            \
    gld16(wp_ +  65536, ld_ +  4096);                                    \
    gld16(wp_ + 131072, ld_ +  8192);                                    \
    gld16(wp_ + 196608, ld_ + 12288);                                    \
} while (0)

template <int PHASE>
__global__ __launch_bounds__(512) void fused4(
    const float* __restrict__ sf32,
    const unsigned short* __restrict__ srelg,
    const unsigned short* __restrict__ Wb,
    const float* __restrict__ biasb,
    unsigned short* __restrict__ srel_out,
    unsigned short* __restrict__ h_out,
    const unsigned short* __restrict__ h_in,
    float* __restrict__ outf,
    const int* __restrict__ perm,
    const int* __restrict__ tile_exp,
    const int* __restrict__ starts8)
{
    __shared__ __align__(16) unsigned short ls[81920];   // 163840 B = full 160 KiB

    const int bid = blockIdx.x;
    int tile;
    if (PHASE == 0) {
        tile = ((bid & 7) << 5) + (bid >> 3);             // XCD swizzle, 256 = 8*32
    } else {
        tile = (bid & 7) * 33 + (bid >> 3);               // XCD swizzle, 264 = 8*33
        if ((tile << 6) >= starts8[0]) return;
    }

    const unsigned short* Wl;
    const float* bl;
    if (PHASE == 0) { Wl = Wb; bl = biasb; }
    else {
        const int e = tile_exp[tile];
        Wl = Wb + ((size_t)e << 20);
        bl = biasb + (e << 11);
    }

    const int t = threadIdx.x;
    const int w = t >> 6;
    const int lane = t & 63;
    const int lr = lane & 15;
    const int kg = lane >> 4;

    const int wbase = ((t >> 2) << 9) + (((t & 3) ^ ((t >> 3) & 3)) << 3);
    const int asrc_c = (t & 56) | ((t ^ (t >> 6)) & 7);
    const int axor = lr & 7;
    int arow_e[4], bvo[4];
#pragma unroll
    for (int m = 0; m < 4; ++m) arow_e[m] = ((m << 4) + lr) << 9;
#pragma unroll
    for (int j = 0; j < 4; ++j)
        bvo[j] = (((w << 6) + (j << 4) + lr) << 5) + ((kg ^ ((lr >> 1) & 3)) << 3);

    // ---- prologue: biases for ALL layers, fenced before any gld16 ----
    float bball[16];
#pragma unroll
    for (int l = 0; l < 4; ++l)
#pragma unroll
        for (int j = 0; j < 4; ++j)
            bball[(l << 2) + j] = bl[(l << 9) + (w << 6) + (j << 4) + lr];
    asm volatile("s_waitcnt vmcnt(0)" ::: "memory");

    // ---- initial A stage ----
    if (PHASE == 0) {
#pragma unroll
        for (int c8 = 0; c8 < 8; ++c8) {
            const int grow = (tile << 6) + (c8 << 3) + (t >> 6);
            const float* sp = sf32 + (((size_t)grow) << 9) + (asrc_c << 3);
            f32x4 v0 = *reinterpret_cast<const f32x4*>(sp);
            f32x4 v1 = *reinterpret_cast<const f32x4*>(sp + 4);
            bf16x8 o;
#pragma unroll
            for (int q = 0; q < 4; ++q) { o[q] = (short)f2bf(v0[q]); o[q + 4] = (short)f2bf(v1[q]); }
            *reinterpret_cast<bf16x8*>(&ls[(c8 << 12) + (t << 3)]) = o;
        }
        asm volatile("s_waitcnt lgkmcnt(0)" ::: "memory");   // my A-writes done
    } else {
#pragma unroll
        for (int c8 = 0; c8 < 8; ++c8) {
            int pr = perm[(tile << 6) + (c8 << 3) + (t >> 6)];
            if (pr < 0) pr = 0;
            gld16(srelg + (((size_t)pr) << 9) + (asrc_c << 3), ls + (c8 << 12) + (t << 3));
        }
    }
    STAGEW(0, 0);
    STAGEW(1, 1);

    f32x4 acc[4][4];
#pragma unroll
    for (int m = 0; m < 4; ++m)
#pragma unroll
        for (int j = 0; j < 4; ++j)
            acc[m][j] = f32x4{0.f, 0.f, 0.f, 0.f};

    // ---- main loop: 64 K-steps (4 layers x 16), 3-buffer, 1 barrier/step ----
    int cur = 0;
    for (int s = 0; s < 64; ++s) {
        if (s < 63) asm volatile("s_waitcnt vmcnt(4)" ::: "memory");
        else        asm volatile("s_waitcnt vmcnt(0)" ::: "memory");
        __builtin_amdgcn_s_barrier();          // buf cur ready; buf nb free (read s-1)
        asm volatile("" ::: "memory");

        int nb = cur + 2; if (nb >= 3) nb -= 3;
        if (s + 2 < 64) STAGEW(s + 2, nb);     // issue early: ~2 steps of flight

        const int st = s & 15;
        const int sb = (st >> 1) << 6;
        const int klo = ((((st & 1) << 2) | kg) ^ axor) << 3;
        const unsigned short* lW = ls + 32768 + (cur << 14);
        bf16x8 af[4], bv[4];
#pragma unroll
        for (int m = 0; m < 4; ++m)
            af[m] = *reinterpret_cast<const bf16x8*>(&ls[arow_e[m] + sb + klo]);
#pragma unroll
        for (int j = 0; j < 4; ++j)
            bv[j] = *reinterpret_cast<const bf16x8*>(&lW[bvo[j]]);
        // no fence here: compiler interleaves counted lgkmcnt with MFMAs
        __builtin_amdgcn_s_setprio(1);
#pragma unroll
        for (int m = 0; m < 4; ++m)
#pragma unroll
            for (int j = 0; j < 4; ++j)
                acc[m][j] = __builtin_amdgcn_mfma_f32_16x16x32_bf16(af[m], bv[j], acc[m][j], 0, 0, 0);
        __builtin_amdgcn_s_setprio(0);

        if (st == 15 && s < 63) {
            // layer boundary: all waves done reading A (pre-MFMA), then rewrite A
            asm volatile("" ::: "memory");
            __builtin_amdgcn_s_barrier();
            asm volatile("" ::: "memory");
            const int lbb = (s >> 4) << 2;
#pragma unroll
            for (int m = 0; m < 4; ++m)
#pragma unroll
                for (int j = 0; j < 4; ++j) {
#pragma unroll
                    for (int reg = 0; reg < 4; ++reg) {
                        const int row = (m << 4) + (kg << 2) + reg;
                        const float v = fmaxf(acc[m][j][reg] + bball[lbb + j], 0.f);
                        const int swc = (w << 3) + (((j << 1) + (lr >> 3)) ^ (row & 7));
                        ls[(row << 9) + (swc << 3) + (lr & 7)] = f2bf(v);
                    }
                    acc[m][j] = f32x4{0.f, 0.f, 0.f, 0.f};
                }
            asm volatile("s_waitcnt lgkmcnt(0)" ::: "memory");
            __builtin_amdgcn_s_barrier();
            asm volatile("" ::: "memory");
        }
        cur = cur + 1 < 3 ? cur + 1 : 0;
    }

    // ---- final epilogue (bball[12..15] = layer-3 bias) ----
    if (PHASE == 0) {
        asm volatile("" ::: "memory");
        __syncthreads();                        // all waves done with final reads
#pragma unroll
        for (int m = 0; m < 4; ++m)
#pragma unroll
            for (int j = 0; j < 4; ++j)
#pragma unroll
                for (int reg = 0; reg < 4; ++reg) {
                    const int row = (m << 4) + (kg << 2) + reg;
                    const int col = (w << 6) + (j << 4) + lr;
                    const float h = fmaxf(acc[m][j][reg] + bball[12 + j], 0.f);
                    const float sv = sf32[(((size_t)((tile << 6) + row)) << 9) + col];
                    const int swc = (w << 3) + (((j << 1) + (lr >> 3)) ^ (row & 7));
                    const int idx = (row << 9) + (swc << 3) + (lr & 7);
                    ls[idx] = f2bf(sv - h);             // srel in A area
                    ls[32768 + idx] = f2bf(h);          // h in W area (64 KB)
                }
        __syncthreads();
#pragma unroll
        for (int c8 = 0; c8 < 8; ++c8) {
            const int row = (c8 << 3) + (t >> 6);
            const size_t go = (((size_t)((tile << 6) + row)) << 9) + (asrc_c << 3);
            bf16x8 va = *reinterpret_cast<const bf16x8*>(&ls[(c8 << 12) + (t << 3)]);
            bf16x8 vh = *reinterpret_cast<const bf16x8*>(&ls[32768 + (c8 << 12) + (t << 3)]);
            *reinterpret_cast<bf16x8*>(&srel_out[go]) = va;
            *reinterpret_cast<bf16x8*>(&h_out[go]) = vh;
        }
    } else {
#pragma unroll
        for (int m = 0; m < 4; ++m) {
#pragma unroll
            for (int reg = 0; reg < 4; ++reg) {
                const int row = (m << 4) + (kg << 2) + reg;
                const int pr = perm[(tile << 6) + row];
                if (pr >= 0) {
#pragma unroll
                    for (int j = 0; j < 4; ++j) {
                        const int col = (w << 6) + (j << 4) + lr;
                        const size_t gi = (((size_t)pr) << 9) + col;
                        outf[gi] = acc[m][j][reg] + bball[12 + j] + bf2f(h_in[gi]);
                    }
                }
            }
        }
    }
}

// ---------------- launch ----------------
extern "C" void kernel_launch(void* const* d_in, const int* in_sizes, int n_in,
                              void* d_out, int out_size, void* d_ws, size_t ws_size,
                              hipStream_t stream)
{
    const float* s     = (const float*)d_in[0];
    const int*   y     = (const int*)d_in[1];
    const float* dec_W = (const float*)d_in[2];
    const float* dec_b = (const float*)d_in[3];
    const float* exp_W = (const float*)d_in[4];
    const float* exp_b = (const float*)d_in[5];
    float* out = (float*)d_out;

    unsigned short* decWb = (unsigned short*)d_ws;              // 4*512*512 bf16 (2 MB)
    unsigned short* expWb = decWb + 4 * 512 * 512;              // 32*512*512 bf16 (16 MB)
    unsigned short* srel  = expWb + 8 * 4 * 512 * 512;          // BB*512 bf16 (16 MB)
    unsigned short* hbuf  = srel + (size_t)BB * 512;            // BB*512 bf16 (16 MB)
    int* perm     = (int*)(hbuf + (size_t)BB * 512);            // PR2
    int* counts   = perm + PR2;                                 // 8
    int* cursors  = counts + 8;                                 // 8
    int* starts   = cursors + 8;                                // 9
    int* tile_exp = starts + 9;                                 // MAXT2

    cvt_bf16<<<256, 256, 0, stream>>>(dec_W, decWb, (4 * 512 * 512) / 4);
    cvt_bf16<<<2048, 256, 0, stream>>>(exp_W, expWb, (8 * 4 * 512 * 512) / 4);

    bucket_init<<<(PR2 + 255) / 256, 256, 0, stream>>>(perm, counts, cursors, tile_exp);
    bucket_count<<<BB / 1024, 1024, 0, stream>>>(y, counts);
    bucket_scan<<<1, 64, 0, stream>>>(counts, starts, tile_exp);
    bucket_scatter<<<BB / 1024, 1024, 0, stream>>>(y, starts, cursors, perm);

    fused4<0><<<256, 512, 0, stream>>>(s, nullptr, decWb, dec_b, srel, hbuf,
                                       nullptr, nullptr, nullptr, nullptr, nullptr);
    fused4<1><<<MAXT2, 512, 0, stream>>>(nullptr, srel, expWb, exp_b, nullptr, nullptr,
                                         hbuf, out, perm, tile_exp, starts + 8);
}